// Round 3
// baseline (331.818 us; speedup 1.0000x reference)
//
#include <hip/hip_runtime.h>

// Problem constants
#define M_DIM 8192   // 4*2048
#define N_DIM 4096   // OUT
#define K_DIM 4096   // IN
#define L_BLK 2097152  // OUT*IN/8
#define K2 8192      // bytes per bf16 row of K_DIM

typedef __attribute__((ext_vector_type(8))) short short8;
typedef __attribute__((ext_vector_type(8))) unsigned short ushort8;
typedef __attribute__((ext_vector_type(4))) float f32x4;

__device__ __forceinline__ unsigned short f2bf(float f) {
  unsigned int u = __float_as_uint(f);
  unsigned int r = (u + 0x7fffu + ((u >> 16) & 1u)) >> 16;
  return (unsigned short)r;
}

__device__ __forceinline__ void gld16(const void* g, void* l) {
  __builtin_amdgcn_global_load_lds(
      (const __attribute__((address_space(1))) void*)g,
      (__attribute__((address_space(3))) void*)l, 16, 0, 0);
}

// ---------------- Dequant: Wq[o,i] = scale[o] * (clip(base + r + zero, 0, 15) - zero[o])
__global__ void dequant_kernel(const float* __restrict__ cb,
                               const int* __restrict__ idx,
                               const int* __restrict__ base,
                               const float* __restrict__ scale,
                               const float* __restrict__ zero,
                               unsigned short* __restrict__ W) {
  const int b = blockIdx.x * 256 + threadIdx.x;   // one per 8-elem block
  const int o = b >> 9;                            // (b*8)/4096
  const float s = scale[o];
  const float z = zero[o];
  const int ci = idx[b];
  const float4* crow = (const float4*)(cb + (size_t)ci * 8);
  float4 c0 = crow[0], c1 = crow[1];
  const int4* brow = (const int4*)(base + (size_t)b * 8);
  int4 b0 = brow[0], b1 = brow[1];
  float a[8]  = {c0.x, c0.y, c0.z, c0.w, c1.x, c1.y, c1.z, c1.w};
  int   bi[8] = {b0.x, b0.y, b0.z, b0.w, b1.x, b1.y, b1.z, b1.w};
  union { unsigned short h[8]; ushort8 v; } u;
#pragma unroll
  for (int d = 0; d < 8; ++d) {
    float sg = 1.0f / (1.0f + __expf(-a[d]));
    float r = fminf(fmaxf(sg * 1.2f - 0.1f, 0.0f), 1.0f);
    float q = fminf(fmaxf((float)bi[d] + r + z, 0.0f), 15.0f);
    u.h[d] = f2bf(s * (q - z));
  }
  *(ushort8*)(W + (size_t)b * 8) = u.v;
}

// ---------------- x f32 -> bf16
__global__ void xconv_kernel(const float* __restrict__ x,
                             unsigned short* __restrict__ xb) {
  const size_t i = (size_t)blockIdx.x * 256 + threadIdx.x;  // 8 floats each
  const float4* X = (const float4*)x;
  float4 a0 = X[i * 2], a1 = X[i * 2 + 1];
  float f[8] = {a0.x, a0.y, a0.z, a0.w, a1.x, a1.y, a1.z, a1.w};
  union { unsigned short h[8]; ushort8 v; } u;
#pragma unroll
  for (int d = 0; d < 8; ++d) u.h[d] = f2bf(f[d]);
  *(ushort8*)(xb + i * 8) = u.v;
}

// ---------------- GEMM: C[m,n] = sum_k A[m,k]*B[n,k] + bias[n]
// 256x256 tile, BK=64, 8 waves (2Mx4N). Software-pipelined 4-phase schedule:
// register fragments read ONE PHASE AHEAD (compiler emits counted lgkmcnt, so
// ds_read completion overlaps MFMA), counted vmcnt with 2-3 phases of latency
// cover, 3 barriers/tile. XOR-swizzled LDS (conflict-free, verified round 2).

#define VMW(N) asm volatile("s_waitcnt vmcnt(" #N ")" ::: "memory")
#define FENCE asm volatile("" ::: "memory")
#define BARM do { FENCE; __builtin_amdgcn_s_barrier(); FENCE; } while (0)

// read B fragments for a whole tile (8 x ds_read_b128)
#define RDB(BF, BUFO) \
  _Pragma("unroll") for (int n = 0; n < 4; ++n) \
  _Pragma("unroll") for (int kk = 0; kk < 2; ++kk) \
    BF[n][kk] = *(const short8*)(lds + (BUFO) + 32768 + \
        (wn * 64 + n * 16 + r16) * 128 + (acol0 ^ (kk << 6)));

// read A fragments for quadrant P (4 x ds_read_b128)
#define RDA(AF, BUFO, P) \
  _Pragma("unroll") for (int mi = 0; mi < 2; ++mi) \
  _Pragma("unroll") for (int kk = 0; kk < 2; ++kk) \
    AF[mi][kk] = *(const short8*)(lds + (BUFO) + \
        (wm * 128 + (2 * (P) + mi) * 16 + r16) * 128 + (acol0 ^ (kk << 6)));

// MFMA quadrant P from fragment regs AF/BF (16 MFMA), pinned in setprio bracket
#define FMQ(P, AF, BF) do { \
  __builtin_amdgcn_s_setprio(1); \
  __builtin_amdgcn_sched_barrier(0); \
  _Pragma("unroll") for (int kk = 0; kk < 2; ++kk) \
  _Pragma("unroll") for (int mi = 0; mi < 2; ++mi) \
  _Pragma("unroll") for (int n = 0; n < 4; ++n) \
    acc[2 * (P) + mi][n] = __builtin_amdgcn_mfma_f32_16x16x32_bf16( \
        AF[mi][kk], BF[n][kk], acc[2 * (P) + mi][n], 0, 0, 0); \
  __builtin_amdgcn_sched_barrier(0); \
  __builtin_amdgcn_s_setprio(0); \
} while (0)

#define STAGE6(NXT, KT) do { \
  stB(NXT, 0, KT); stB(NXT, 1, KT); stB(NXT, 2, KT); stB(NXT, 3, KT); \
  stA(NXT, 0, KT); stA(NXT, 2, KT); } while (0)
#define STAGE2(NXT, KT) do { stA(NXT, 1, KT); stA(NXT, 3, KT); } while (0)

// One K-tile iteration. BFC = this tile's B frags, BFN = next tile's.
// CUR/NXT are LDS byte offsets (compile-time). KT = next tile index (staged).
#define ITER(BFC, BFN, CUR, NXT, KT) do { \
  /* ph0: q0 compute; read q1; stage 6 of next tile */ \
  RDA(afB, CUR, 1); STAGE6(NXT, KT); FMQ(0, afA, BFC); VMW(6); BARM; \
  /* ph1: q1; read q2 (chunks 1,3 of cur now safe); stage 2 */ \
  RDA(afA, CUR, 2); STAGE2(NXT, KT); FMQ(1, afB, BFC); \
  /* ph2: q2; read q3 */ \
  RDA(afB, CUR, 3); FMQ(2, afA, BFC); VMW(2); BARM; \
  /* ph3: q3; read next tile's B + q0 (staged data safe after VMW(2)+BARM) */ \
  RDB(BFN, NXT); RDA(afA, NXT, 0); FMQ(3, afB, BFC); BARM; \
} while (0)

__global__ __launch_bounds__(512, 2)
void gemm_bt(const unsigned short* __restrict__ A,
             const unsigned short* __restrict__ B,
             const float* __restrict__ bias,
             float* __restrict__ C) {
  __shared__ char lds[131072];  // 2 bufs x (A 32K | B 32K)
  const int tid = threadIdx.x;
  const int lane = tid & 63;
  const int w = tid >> 6;       // 0..7
  const int wm = w >> 2;        // 0..1  (wave row: 128 rows each)
  const int wn = w & 3;         // 0..3  (wave col: 64 cols each)
  const int r16 = lane & 15;
  const int g = lane >> 4;
  const int acol0 = (g << 4) ^ ((r16 & 7) << 4);

  // XCD-bijective block swizzle (512 % 8 == 0), bn-major chunks for B-panel L2 reuse
  const int s = (int)blockIdx.x;
  const int wg = (s & 7) * 64 + (s >> 3);
  const int bm = wg & 31;
  const int bn = wg >> 5;

  const char* Abase = (const char*)A + (size_t)bm * 256 * K2;
  const char* Bbase = (const char*)B + (size_t)bn * 256 * K2;

  // staging: chunk = 64 rows x 128 B; thread covers 16 B; wave-uniform dest
  const int strow = tid >> 3;
  const int scol = ((tid & 7) * 16) ^ ((strow & 7) << 4);  // inverse-swizzled src
  const int sdst = w * 1024;

  auto stA = [&](int bo, int c, int kt) {
    gld16(Abase + (size_t)(c * 64 + strow) * K2 + kt * 128 + scol,
          lds + bo + c * 8192 + sdst);
  };
  auto stB = [&](int bo, int c, int kt) {
    gld16(Bbase + (size_t)(c * 64 + strow) * K2 + kt * 128 + scol,
          lds + bo + 32768 + c * 8192 + sdst);
  };

  f32x4 acc[8][4] = {};
  short8 bfA[4][2], bfB[4][2];
  short8 afA[2][2], afB[2][2];

  // prologue: stage tile 0 into buf 0 (same issue order as loop), drain, read q0
  STAGE6(0, 0); STAGE2(0, 0);
  VMW(0); BARM;
  RDB(bfA, 0); RDA(afA, 0, 0);

  // tiles 0..61 as 31 even/odd pairs (B-frag buffer alternates per tile)
  for (int tp = 0; tp < 31; ++tp) {
    ITER(bfA, bfB, 0, 65536, 2 * tp + 1);
    ITER(bfB, bfA, 65536, 0, 2 * tp + 2);
  }
  // tile 62 (stages tile 63)
  ITER(bfA, bfB, 0, 65536, 63);
  // tile 63 tail: no staging; VMW(0) drains tile-63 A1,A3 before q2/q3 reads
  RDA(afB, 65536, 1); FMQ(0, afA, bfB); VMW(0); BARM;
  RDA(afA, 65536, 2); FMQ(1, afB, bfB);
  RDA(afB, 65536, 3); FMQ(2, afA, bfB);
  FMQ(3, afB, bfB);

  FENCE;  // keep epilogue loads from hoisting into the loop (vmcnt bookkeeping)

  // epilogue: C/D layout col = lane&15, row = (lane>>4)*4 + j  [m89-verified]
  const int cb0 = bn * 256 + wn * 64 + r16;
  float bv[4];
#pragma unroll
  for (int n = 0; n < 4; ++n) bv[n] = bias[cb0 + n * 16];
#pragma unroll
  for (int m = 0; m < 8; ++m) {
#pragma unroll
    for (int j = 0; j < 4; ++j) {
      int row = bm * 256 + wm * 128 + m * 16 + g * 4 + j;
      float* Crow = C + (size_t)row * N_DIM + cb0;
#pragma unroll
      for (int n = 0; n < 4; ++n) Crow[n * 16] = acc[m][n][j] + bv[n];
    }
  }
}

extern "C" void kernel_launch(void* const* d_in, const int* in_sizes, int n_in,
                              void* d_out, int out_size, void* d_ws, size_t ws_size,
                              hipStream_t stream) {
  const float* x     = (const float*)d_in[0];
  const float* cb    = (const float*)d_in[1];
  const int*   idx   = (const int*)d_in[2];
  const int*   base  = (const int*)d_in[3];
  const float* scale = (const float*)d_in[4];
  const float* zero  = (const float*)d_in[5];
  const float* bias  = (const float*)d_in[6];
  float* out = (float*)d_out;

  // workspace: Wq bf16 [N,K] (32 MiB) | x bf16 [M,K] (64 MiB)
  unsigned short* Wq = (unsigned short*)d_ws;
  unsigned short* Xb = (unsigned short*)((char*)d_ws + (size_t)N_DIM * K_DIM * 2);

  dequant_kernel<<<L_BLK / 256, 256, 0, stream>>>(cb, idx, base, scale, zero, Wq);
  xconv_kernel<<<(M_DIM * K_DIM / 8) / 256, 256, 0, stream>>>(x, Xb);
  gemm_bt<<<(M_DIM / 256) * (N_DIM / 256), 512, 0, stream>>>(Xb, Wq, bias, out);
}

// Round 4
// 310.199 us; speedup vs baseline: 1.0697x; 1.0697x over previous
//
#include <hip/hip_runtime.h>

// Problem constants
#define M_DIM 8192   // 4*2048
#define N_DIM 4096   // OUT
#define K_DIM 4096   // IN
#define L_BLK 2097152  // OUT*IN/8
#define K2 8192      // bytes per bf16 row of K_DIM

typedef __attribute__((ext_vector_type(8))) short short8;
typedef __attribute__((ext_vector_type(8))) unsigned short ushort8;
typedef __attribute__((ext_vector_type(4))) float f32x4;

__device__ __forceinline__ unsigned short f2bf(float f) {
  unsigned int u = __float_as_uint(f);
  unsigned int r = (u + 0x7fffu + ((u >> 16) & 1u)) >> 16;
  return (unsigned short)r;
}

__device__ __forceinline__ void gld16(const void* g, void* l) {
  __builtin_amdgcn_global_load_lds(
      (const __attribute__((address_space(1))) void*)g,
      (__attribute__((address_space(3))) void*)l, 16, 0, 0);
}

// ---------------- Dequant: Wq[o,i] = scale[o] * (clip(base + r + zero, 0, 15) - zero[o])
__global__ void dequant_kernel(const float* __restrict__ cb,
                               const int* __restrict__ idx,
                               const int* __restrict__ base,
                               const float* __restrict__ scale,
                               const float* __restrict__ zero,
                               unsigned short* __restrict__ W) {
  const int b = blockIdx.x * 256 + threadIdx.x;   // one per 8-elem block
  const int o = b >> 9;                            // (b*8)/4096
  const float s = scale[o];
  const float z = zero[o];
  const int ci = idx[b];
  const float4* crow = (const float4*)(cb + (size_t)ci * 8);
  float4 c0 = crow[0], c1 = crow[1];
  const int4* brow = (const int4*)(base + (size_t)b * 8);
  int4 b0 = brow[0], b1 = brow[1];
  float a[8]  = {c0.x, c0.y, c0.z, c0.w, c1.x, c1.y, c1.z, c1.w};
  int   bi[8] = {b0.x, b0.y, b0.z, b0.w, b1.x, b1.y, b1.z, b1.w};
  union { unsigned short h[8]; ushort8 v; } u;
#pragma unroll
  for (int d = 0; d < 8; ++d) {
    float sg = 1.0f / (1.0f + __expf(-a[d]));
    float r = fminf(fmaxf(sg * 1.2f - 0.1f, 0.0f), 1.0f);
    float q = fminf(fmaxf((float)bi[d] + r + z, 0.0f), 15.0f);
    u.h[d] = f2bf(s * (q - z));
  }
  *(ushort8*)(W + (size_t)b * 8) = u.v;
}

// ---------------- x f32 -> bf16
__global__ void xconv_kernel(const float* __restrict__ x,
                             unsigned short* __restrict__ xb) {
  const size_t i = (size_t)blockIdx.x * 256 + threadIdx.x;  // 8 floats each
  const float4* X = (const float4*)x;
  float4 a0 = X[i * 2], a1 = X[i * 2 + 1];
  float f[8] = {a0.x, a0.y, a0.z, a0.w, a1.x, a1.y, a1.z, a1.w};
  union { unsigned short h[8]; ushort8 v; } u;
#pragma unroll
  for (int d = 0; d < 8; ++d) u.h[d] = f2bf(f[d]);
  *(ushort8*)(xb + i * 8) = u.v;
}

// ---------------- GEMM: C[m,n] = sum_k A[m,k]*B[n,k] + bias[n]
// 256x256 tile, BK=64, 8 waves (2Mx4N). Faithful m201 8-phase schedule:
// per phase {this-phase ds_reads; stage ONE half-tile (2 gld16/thr); BAR;
// lgkm0; setprio+16 MFMA+setprio; BAR}; ONE vmcnt(6) per K-tile at P4 with
// 4-7 phases of latency cover (staging 1.5 tiles ahead). Race-free by
// barrier construction: A-q3 reads moved to P3 so P4's A0-stage is safe.
// XOR-swizzled LDS (bank-conflict-free, verified round 2).

#define VMW(N) asm volatile("s_waitcnt vmcnt(" #N ")" ::: "memory")
#define FENCE asm volatile("" ::: "memory")
#define BAR do { FENCE; __builtin_amdgcn_s_barrier(); FENCE; } while (0)
#define LGKM0 do { asm volatile("s_waitcnt lgkmcnt(0)" ::: "memory"); \
                   __builtin_amdgcn_sched_barrier(0); } while (0)

// read B fragments for a whole tile (8 x ds_read_b128)
#define RDB(BF, BUFO) \
  _Pragma("unroll") for (int n = 0; n < 4; ++n) \
  _Pragma("unroll") for (int kk = 0; kk < 2; ++kk) \
    BF[n][kk] = *(const short8*)(lds + (BUFO) + 32768 + \
        (wn * 64 + n * 16 + r16) * 128 + (acol0 ^ (kk << 6)));

// read A fragments for quadrant P (4 x ds_read_b128)
#define RDA(AF, BUFO, P) \
  _Pragma("unroll") for (int mi = 0; mi < 2; ++mi) \
  _Pragma("unroll") for (int kk = 0; kk < 2; ++kk) \
    AF[mi][kk] = *(const short8*)(lds + (BUFO) + \
        (wm * 128 + (2 * (P) + mi) * 16 + r16) * 128 + (acol0 ^ (kk << 6)));

// MFMA quadrant P (16 MFMA), pinned in setprio bracket
#define FMQ(P, AF, BF) do { \
  __builtin_amdgcn_s_setprio(1); \
  __builtin_amdgcn_sched_barrier(0); \
  _Pragma("unroll") for (int kk = 0; kk < 2; ++kk) \
  _Pragma("unroll") for (int mi = 0; mi < 2; ++mi) \
  _Pragma("unroll") for (int n = 0; n < 4; ++n) \
    acc[2 * (P) + mi][n] = __builtin_amdgcn_mfma_f32_16x16x32_bf16( \
        AF[mi][kk], BF[n][kk], acc[2 * (P) + mi][n], 0, 0, 0); \
  __builtin_amdgcn_sched_barrier(0); \
  __builtin_amdgcn_s_setprio(0); \
} while (0)

// One K-tile (4 phases). CUR/NXT compile-time LDS offsets; T = tile index.
// Stage stream: P1 -> A-half1 of t+1 (into NXT); P2/P3/P4 -> B0/B1/A0 of t+2
// (into CUR). vmcnt(6) once, at P4 (keeps exactly the 3 halves staged P2-P4).
#define ITER(CUR, NXT, T) do { \
  /* P1 */ RDB(bf, CUR); RDA(afA, CUR, 0); \
  stA(NXT, 2, (T) + 1); stA(NXT, 3, (T) + 1); \
  BAR; LGKM0; FMQ(0, afA, bf); BAR; \
  /* P2 */ RDA(afA, CUR, 1); \
  stB(CUR, 0, (T) + 2); stB(CUR, 1, (T) + 2); \
  BAR; LGKM0; FMQ(1, afA, bf); BAR; \
  /* P3 */ RDA(afA, CUR, 2); RDA(afB, CUR, 3); \
  stB(CUR, 2, (T) + 2); stB(CUR, 3, (T) + 2); \
  BAR; LGKM0; FMQ(2, afA, bf); BAR; \
  /* P4 */ stA(CUR, 0, (T) + 2); stA(CUR, 1, (T) + 2); \
  VMW(6); BAR; LGKM0; FMQ(3, afB, bf); BAR; \
} while (0)

__global__ __launch_bounds__(512, 2)
void gemm_bt(const unsigned short* __restrict__ A,
             const unsigned short* __restrict__ B,
             const float* __restrict__ bias,
             float* __restrict__ C) {
  __shared__ char lds[131072];  // 2 bufs x (A 32K | B 32K)
  const int tid = threadIdx.x;
  const int lane = tid & 63;
  const int w = tid >> 6;       // 0..7
  const int wm = w >> 2;        // 0..1  (wave row: 128 rows each)
  const int wn = w & 3;         // 0..3  (wave col: 64 cols each)
  const int r16 = lane & 15;
  const int g = lane >> 4;
  const int acol0 = (g << 4) ^ ((r16 & 7) << 4);

  // XCD-bijective block swizzle (512 % 8 == 0), bn-major chunks for B-panel L2 reuse
  const int s = (int)blockIdx.x;
  const int wg = (s & 7) * 64 + (s >> 3);
  const int bm = wg & 31;
  const int bn = wg >> 5;

  const char* Abase = (const char*)A + (size_t)bm * 256 * K2;
  const char* Bbase = (const char*)B + (size_t)bn * 256 * K2;

  // staging: chunk = 64 rows x 128 B = 8 KiB; one gld16 per thread per chunk;
  // half-tile = 2 chunks = 2 gld16/thread. Inverse-swizzled global source.
  const int strow = tid >> 3;
  const int scol = ((tid & 7) * 16) ^ ((strow & 7) << 4);
  const int sdst = w * 1024;

  auto stA = [&](int bo, int c, int kt) {
    gld16(Abase + (size_t)(c * 64 + strow) * K2 + kt * 128 + scol,
          lds + bo + c * 8192 + sdst);
  };
  auto stB = [&](int bo, int c, int kt) {
    gld16(Bbase + (size_t)(c * 64 + strow) * K2 + kt * 128 + scol,
          lds + bo + 32768 + c * 8192 + sdst);
  };

  f32x4 acc[8][4] = {};
  short8 bf[4][2];
  short8 afA[2][2], afB[2][2];

  // prologue: tile0 all 4 halves (B0,B1,A0,A1) + tile1's B0,B1,A0 = 14 loads;
  // vmcnt(6) retires tile0's 8, keeps tile1's 6 in flight.
  stB(0, 0, 0); stB(0, 1, 0); stB(0, 2, 0); stB(0, 3, 0);
  stA(0, 0, 0); stA(0, 1, 0); stA(0, 2, 0); stA(0, 3, 0);
  stB(65536, 0, 1); stB(65536, 1, 1); stB(65536, 2, 1); stB(65536, 3, 1);
  stA(65536, 0, 1); stA(65536, 1, 1);
  VMW(6); BAR;

  // tiles 0..61 as 31 even/odd pairs
  for (int tp = 0; tp < 31; ++tp) {
    ITER(0, 65536, 2 * tp);
    ITER(65536, 0, 2 * tp + 1);
  }
  // tile 62: stages only A-half1 of t63 at P1; VMW(0) at P4 drains t63 fully
  RDB(bf, 0); RDA(afA, 0, 0);
  stA(65536, 2, 63); stA(65536, 3, 63);
  BAR; LGKM0; FMQ(0, afA, bf); BAR;
  RDA(afA, 0, 1);
  BAR; LGKM0; FMQ(1, afA, bf); BAR;
  RDA(afA, 0, 2); RDA(afB, 0, 3);
  BAR; LGKM0; FMQ(2, afA, bf); BAR;
  VMW(0); BAR; LGKM0; FMQ(3, afB, bf); BAR;
  // tile 63: reads only
  RDB(bf, 65536); RDA(afA, 65536, 0);
  LGKM0; FMQ(0, afA, bf);
  RDA(afA, 65536, 1);
  LGKM0; FMQ(1, afA, bf);
  RDA(afA, 65536, 2); RDA(afB, 65536, 3);
  LGKM0; FMQ(2, afA, bf);
  FMQ(3, afB, bf);

  FENCE;

  // epilogue: C/D layout col = lane&15, row = (lane>>4)*4 + j  [m89-verified]
  const int cb0 = bn * 256 + wn * 64 + r16;
  float bv[4];
#pragma unroll
  for (int n = 0; n < 4; ++n) bv[n] = bias[cb0 + n * 16];
#pragma unroll
  for (int m = 0; m < 8; ++m) {
#pragma unroll
    for (int j = 0; j < 4; ++j) {
      int row = bm * 256 + wm * 128 + m * 16 + g * 4 + j;
      float* Crow = C + (size_t)row * N_DIM + cb0;
#pragma unroll
      for (int n = 0; n < 4; ++n) Crow[n * 16] = acc[m][n][j] + bv[n];
    }
  }
}

extern "C" void kernel_launch(void* const* d_in, const int* in_sizes, int n_in,
                              void* d_out, int out_size, void* d_ws, size_t ws_size,
                              hipStream_t stream) {
  const float* x     = (const float*)d_in[0];
  const float* cb    = (const float*)d_in[1];
  const int*   idx   = (const int*)d_in[2];
  const int*   base  = (const int*)d_in[3];
  const float* scale = (const float*)d_in[4];
  const float* zero  = (const float*)d_in[5];
  const float* bias  = (const float*)d_in[6];
  float* out = (float*)d_out;

  // workspace: Wq bf16 [N,K] (32 MiB) | x bf16 [M,K] (64 MiB)
  unsigned short* Wq = (unsigned short*)d_ws;
  unsigned short* Xb = (unsigned short*)((char*)d_ws + (size_t)N_DIM * K_DIM * 2);

  dequant_kernel<<<L_BLK / 256, 256, 0, stream>>>(cb, idx, base, scale, zero, Wq);
  xconv_kernel<<<(M_DIM * K_DIM / 8) / 256, 256, 0, stream>>>(x, Xb);
  gemm_bt<<<(M_DIM / 256) * (N_DIM / 256), 512, 0, stream>>>(Xb, Wq, bias, out);
}